// Round 1
// 540.445 us; speedup vs baseline: 1.0070x; 1.0070x over previous
//
#include <hip/hip_runtime.h>

#define SEQ 128
#define DIM 1024
#define TOPK 51
#define DECAY 0.99f
#define INHIB 1.5f

typedef float v4f __attribute__((ext_vector_type(4)));

// ---------------- Kernel A: per-row sparsify (relu + top-k threshold) --------
// One block (256 threads) per row. Exact k-th-largest via 4-pass 8-bit radix
// select on the float bit pattern (monotonic for non-negative floats).
// Bin selection: wave-level __shfl_down suffix-scan (no barriers) + one
// cross-wave LDS combine -> 3 barriers/pass (vs ~19 for Hillis-Steele).
__global__ __launch_bounds__(256) void sparsify_kernel(
    const float* __restrict__ emb, float* __restrict__ s_out,
    int* __restrict__ nnz_idx, int* __restrict__ nnz_cnt)
{
    const int t    = blockIdx.x;
    const int tid  = threadIdx.x;
    const int lane = tid & 63;
    const int wave = tid >> 6;
    const float* x = emb + t * DIM;

    float    v[4];
    unsigned u[4];
#pragma unroll
    for (int e = 0; e < 4; ++e) {
        float val = fmaxf(x[e * 256 + tid], 0.0f);   // relu
        v[e] = val;
        u[e] = __float_as_uint(val);
    }

    __shared__ unsigned hist[256];
    __shared__ unsigned wtot[4];
    __shared__ unsigned sh_prefix;
    __shared__ unsigned sh_k;
    __shared__ int      sh_cnt;
    if (tid == 0) { sh_prefix = 0u; sh_k = TOPK; sh_cnt = 0; }
    hist[tid] = 0u;
    __syncthreads();

    for (int pass = 0; pass < 4; ++pass) {
        const int shift = 24 - 8 * pass;
        const unsigned prefix = sh_prefix;
        const unsigned k      = sh_k;
#pragma unroll
        for (int e = 0; e < 4; ++e) {
            bool ok;
            if (pass == 0) ok = true;
            else           ok = ((u[e] >> (shift + 8)) == (prefix >> (shift + 8)));
            if (ok) atomicAdd(&hist[(u[e] >> shift) & 255u], 1u);
        }
        __syncthreads();

        // Wave-local inclusive suffix-sum over 64 bins (lane i: sum bins i..63)
        unsigned val = hist[tid];
#pragma unroll
        for (int off = 1; off < 64; off <<= 1) {
            unsigned tmp = __shfl_down(val, off, 64);
            if (lane + off < 64) val += tmp;
        }
        if (lane == 0) wtot[wave] = val;   // wave total = suffix from its bin 0
        __syncthreads();

        unsigned addHigher = 0u;
        for (int w = wave + 1; w < 4; ++w) addHigher += wtot[w];
        const unsigned scanFull = val + addHigher;          // suffix over all 256
        const unsigned nxtWithin = __shfl_down(scanFull, 1, 64);
        const unsigned nxt = (lane == 63) ? addHigher : nxtWithin;
        // scanFull non-increasing, scanFull[0]>=k, virtual scanFull[256]=0:
        // exactly one crossing -> bin holding the k-th largest.
        if (scanFull >= k && nxt < k) {
            sh_prefix = prefix | ((unsigned)tid << shift);
            sh_k      = k - nxt;
        }
        hist[tid] = 0u;   // re-zero for next pass (no one reads hist anymore)
        __syncthreads();  // publishes sh_prefix/sh_k AND hist zeroing
    }

    const float thr = __uint_as_float(sh_prefix);
#pragma unroll
    for (int e = 0; e < 4; ++e) {
        const int idx = e * 256 + tid;
        const float sval = (v[e] >= thr) ? v[e] : 0.0f;
        s_out[t * DIM + idx] = sval;
        if (sval > 0.0f) {
            int pos = atomicAdd(&sh_cnt, 1);
            nnz_idx[t * DIM + pos] = idx;
        }
    }
    __syncthreads();
    if (tid == 0) nnz_cnt[t] = sh_cnt;
}

// ---------------- Kernel B: element-parallel state evolution -----------------
// state_t[i,j] = relu(DECAY*state_{t-1}[i,j] + f_t * s_t[i] * s_t[j])
// Each thread owns a 2(i) x 4(j) register tile; block covers full j (1024)
// and 2 i-rows; grid = DIM/2 = 512 blocks -> 2 blocks/CU, 8 waves/CU.
// Write-BW bound: 512 MiB mandatory snapshots @ ~6.2 TB/s ≈ 86 us floor.
// R4: stores are now NON-TEMPORAL (nt bit, evict-first) — the snapshots are
// written once, read back sparsely (5% of rows) by drift, so retaining dirty
// lines in L2 only adds writeback bookkeeping. The harness fill kernel
// (same store width, streaming) achieves 6.23 TB/s; this mirrors it.
__global__ __launch_bounds__(256) void evolve_kernel(
    const float* __restrict__ s, const float* __restrict__ con,
    float* __restrict__ states)
{
    const int i0 = blockIdx.x * 2;
    const int j0 = threadIdx.x * 4;

    float st[2][4];
#pragma unroll
    for (int a = 0; a < 2; ++a)
#pragma unroll
        for (int b = 0; b < 4; ++b) st[a][b] = 0.0f;

    for (int t = 0; t < SEQ; ++t) {
        const float f = 1.0f - INHIB * con[t];
        const float4 sj = *(const float4*)(s + t * DIM + j0);
        float si[2];
#pragma unroll
        for (int a = 0; a < 2; ++a) si[a] = s[t * DIM + i0 + a] * f;

        float* outp = states + (size_t)t * DIM * DIM;
#pragma unroll
        for (int a = 0; a < 2; ++a) {
            v4f o;
            o[0] = fmaxf(0.0f, DECAY * st[a][0] + si[a] * sj.x);
            o[1] = fmaxf(0.0f, DECAY * st[a][1] + si[a] * sj.y);
            o[2] = fmaxf(0.0f, DECAY * st[a][2] + si[a] * sj.z);
            o[3] = fmaxf(0.0f, DECAY * st[a][3] + si[a] * sj.w);
            st[a][0] = o[0]; st[a][1] = o[1]; st[a][2] = o[2]; st[a][3] = o[3];
            __builtin_nontemporal_store(
                o, (v4f*)(outp + (size_t)(i0 + a) * DIM + j0));
        }
    }
}

// ---------------- Kernel C: sparse drift ------------------------------------
// drift_t = || s_t - s_t @ state_{t-1} ||_2 ; only ~TOPK rows of state matter.
// One block (256 threads) per t; thread owns 4 consecutive j (float4 loads,
// 1KB/wave). Index/value list staged in LDS so row loads are independent.
// R4: unroll 4 -> 8 (8 HBM loads in flight per thread, ~7 serial latency
// steps instead of ~13 for the 51-row list). R3's 4-way j-split regressed:
// it did NOT shorten the n-loop, only shrank loads to 4B/lane — keep 1 block/t.
__global__ __launch_bounds__(256) void drift_kernel(
    const float* __restrict__ s, const int* __restrict__ nnz_idx,
    const int* __restrict__ nnz_cnt, const float* __restrict__ states,
    float* __restrict__ drift)
{
    const int t   = blockIdx.x;
    const int tid = threadIdx.x;
    const int j0  = tid * 4;

    __shared__ int   sh_ix[DIM];
    __shared__ float sh_sv[DIM];

    float e0 = 0.f, e1 = 0.f, e2 = 0.f, e3 = 0.f;
    if (t > 0) {                       // t is block-uniform: no divergent sync
        const int cnt = nnz_cnt[t];
        for (int n = tid; n < cnt; n += 256) {
            const int i = nnz_idx[t * DIM + n];
            sh_ix[n] = i;
            sh_sv[n] = s[t * DIM + i];
        }
        __syncthreads();

        const float* prev = states + (size_t)(t - 1) * DIM * DIM;
        int n = 0;
        for (; n + 8 <= cnt; n += 8) {
            float4 r[8];
            float  a[8];
#pragma unroll
            for (int q = 0; q < 8; ++q) {
                const int i = sh_ix[n + q];
                a[q] = sh_sv[n + q];
                r[q] = *(const float4*)(prev + (size_t)i * DIM + j0);
            }
#pragma unroll
            for (int q = 0; q < 8; ++q) {
                e0 += a[q] * r[q].x;
                e1 += a[q] * r[q].y;
                e2 += a[q] * r[q].z;
                e3 += a[q] * r[q].w;
            }
        }
        for (; n + 4 <= cnt; n += 4) {
            const int ia = sh_ix[n],     ib = sh_ix[n + 1];
            const int ic = sh_ix[n + 2], id = sh_ix[n + 3];
            const float aa = sh_sv[n],     ab = sh_sv[n + 1];
            const float ac = sh_sv[n + 2], ad = sh_sv[n + 3];
            const float4 ra = *(const float4*)(prev + (size_t)ia * DIM + j0);
            const float4 rb = *(const float4*)(prev + (size_t)ib * DIM + j0);
            const float4 rc = *(const float4*)(prev + (size_t)ic * DIM + j0);
            const float4 rd = *(const float4*)(prev + (size_t)id * DIM + j0);
            e0 += aa * ra.x + ab * rb.x + ac * rc.x + ad * rd.x;
            e1 += aa * ra.y + ab * rb.y + ac * rc.y + ad * rd.y;
            e2 += aa * ra.z + ab * rb.z + ac * rc.z + ad * rd.z;
            e3 += aa * ra.w + ab * rb.w + ac * rc.w + ad * rd.w;
        }
        for (; n < cnt; ++n) {
            const int i = sh_ix[n];
            const float si = sh_sv[n];
            const float4 r = *(const float4*)(prev + (size_t)i * DIM + j0);
            e0 += si * r.x; e1 += si * r.y; e2 += si * r.z; e3 += si * r.w;
        }
    }
    const float4 sj = *(const float4*)(s + t * DIM + j0);
    const float d0 = sj.x - e0, d1 = sj.y - e1, d2 = sj.z - e2, d3 = sj.w - e3;
    float local = d0 * d0 + d1 * d1 + d2 * d2 + d3 * d3;

#pragma unroll
    for (int off = 32; off > 0; off >>= 1)
        local += __shfl_down(local, off, 64);

    __shared__ float wsum[4];
    if ((tid & 63) == 0) wsum[tid >> 6] = local;
    __syncthreads();
    if (tid == 0) drift[t] = sqrtf(wsum[0] + wsum[1] + wsum[2] + wsum[3]);
}

extern "C" void kernel_launch(void* const* d_in, const int* in_sizes, int n_in,
                              void* d_out, int out_size, void* d_ws, size_t ws_size,
                              hipStream_t stream)
{
    const float* emb = (const float*)d_in[0];     // [S, D] fp32
    const float* con = (const float*)d_in[1];     // [S]    fp32

    float* drift  = (float*)d_out;                // [S]
    float* states = (float*)d_out + SEQ;          // [S, D, D]

    float* s_buf   = (float*)d_ws;                                   // S*D floats
    int*   nnz_idx = (int*)((char*)d_ws + (size_t)SEQ * DIM * 4);    // S*D ints
    int*   nnz_cnt = (int*)((char*)d_ws + (size_t)2 * SEQ * DIM * 4);// S ints

    sparsify_kernel<<<SEQ, 256, 0, stream>>>(emb, s_buf, nnz_idx, nnz_cnt);
    evolve_kernel<<<DIM / 2, 256, 0, stream>>>(s_buf, con, states);
    drift_kernel<<<SEQ, 256, 0, stream>>>(s_buf, nnz_idx, nnz_cnt, states, drift);
}